// Round 7
// baseline (1468.100 us; speedup 1.0000x reference)
//
#include <hip/hip_runtime.h>

#define IN_DIM 128
#define HID    64
#define OUTD   32

#define BSHIFT 9
#define BNODES 512                 // 1 << BSHIFT
#define NB     196                 // ceil(100000 / 512)
#define CHUNK  4096                // edges per k_bscatter block

// ---- bf16 helpers (RNE pack, shift-unpack) ----

__device__ __forceinline__ unsigned bfp2(float x, float y) {
    unsigned a = __float_as_uint(x); a = a + 0x7FFF + ((a >> 16) & 1);
    unsigned b = __float_as_uint(y); b = b + 0x7FFF + ((b >> 16) & 1);
    return (a >> 16) | (b & 0xFFFF0000u);
}

__device__ __forceinline__ void acc8(float* f, uint4 q) {
    f[0] += __uint_as_float(q.x << 16); f[1] += __uint_as_float(q.x & 0xFFFF0000u);
    f[2] += __uint_as_float(q.y << 16); f[3] += __uint_as_float(q.y & 0xFFFF0000u);
    f[4] += __uint_as_float(q.z << 16); f[5] += __uint_as_float(q.z & 0xFFFF0000u);
    f[6] += __uint_as_float(q.w << 16); f[7] += __uint_as_float(q.w & 0xFFFF0000u);
}

// ================= Pass A: coarse bucket counts =================

__launch_bounds__(256)
__global__ void k_bcount(const int* __restrict__ dst, int* __restrict__ bucketCnt, int E) {
    __shared__ int h[NB];
    int t = threadIdx.x;
    for (int i = t; i < NB; i += 256) h[i] = 0;
    __syncthreads();
    int stride = gridDim.x * blockDim.x;
    for (int e = blockIdx.x * blockDim.x + t; e < E; e += stride)
        atomicAdd(&h[__builtin_nontemporal_load(dst + e) >> BSHIFT], 1);
    __syncthreads();
    for (int i = t; i < NB; i += 256)
        if (h[i]) atomicAdd(&bucketCnt[i], h[i]);
}

// ================= scan bucket counts -> bases & cursors =================

__global__ void k_bscan(const int* __restrict__ bucketCnt, int* __restrict__ bucketBase,
                        int* __restrict__ bucketCursor, int* __restrict__ rs, int N, int E) {
    __shared__ int sd[256];
    int t = threadIdx.x;
    int v = (t < NB) ? bucketCnt[t] : 0;
    sd[t] = v;
    __syncthreads();
    for (int off = 1; off < 256; off <<= 1) {
        int u = (t >= off) ? sd[t - off] : 0;
        __syncthreads();
        sd[t] += u;
        __syncthreads();
    }
    int excl = sd[t] - v;
    if (t < NB) { bucketBase[t] = excl; bucketCursor[t] = excl; }
    if (t == 0) { bucketBase[NB] = E; rs[N] = E; }
}

// ================= Pass B: scatter edges into buckets (packed src<<9 | dst_local) =================

__launch_bounds__(256)
__global__ void k_bscatter(const int* __restrict__ src, const int* __restrict__ dst,
                           int* __restrict__ bucketCursor, int* __restrict__ ebuf, int E) {
    __shared__ int h[NB];
    __shared__ int lbase[NB];
    __shared__ int lcur[NB];
    int t = threadIdx.x;
    int base = blockIdx.x * CHUNK;
    int end = min(base + CHUNK, E);
    for (int i = t; i < NB; i += 256) { h[i] = 0; lcur[i] = 0; }
    __syncthreads();
    for (int i = base + t; i < end; i += 256)
        atomicAdd(&h[dst[i] >> BSHIFT], 1);
    __syncthreads();
    for (int i = t; i < NB; i += 256)
        lbase[i] = h[i] ? atomicAdd(&bucketCursor[i], h[i]) : 0;
    __syncthreads();
    for (int i = base + t; i < end; i += 256) {
        int d = dst[i];
        int b = d >> BSHIFT;
        int off = atomicAdd(&lcur[b], 1);
        ebuf[lbase[b] + off] = (src[i] << BSHIFT) | (d & (BNODES - 1));
    }
}

// ================= Pass C: per-bucket fine CSR build + rs + dinv =================

__launch_bounds__(256)
__global__ void k_bfinal(const int* __restrict__ ebuf, const int* __restrict__ bucketBase,
                         int* __restrict__ rs, float* __restrict__ dinv,
                         int* __restrict__ csr, int N) {
    __shared__ int hist[BNODES];
    __shared__ int rsl[BNODES];
    __shared__ int ssum[256];
    int t = threadIdx.x;
    int b = blockIdx.x;
    int nodeBase = b << BSHIFT;
    int ebase = bucketBase[b], eend = bucketBase[b + 1];

    hist[t] = 0; hist[t + 256] = 0;
    __syncthreads();
    for (int i = ebase + t; i < eend; i += 256)
        atomicAdd(&hist[__builtin_nontemporal_load(ebuf + i) & (BNODES - 1)], 1);
    __syncthreads();

    int h0 = hist[2 * t], h1 = hist[2 * t + 1];
    ssum[t] = h0 + h1;
    __syncthreads();
    for (int off = 1; off < 256; off <<= 1) {
        int u = (t >= off) ? ssum[t - off] : 0;
        __syncthreads();
        ssum[t] += u;
        __syncthreads();
    }
    int excl = ssum[t] - h0 - h1;
    rsl[2 * t]     = excl;
    rsl[2 * t + 1] = excl + h0;

    int n0 = nodeBase + 2 * t, n1 = n0 + 1;
    if (n0 < N) { rs[n0] = ebase + excl;      dinv[n0] = rsqrtf((float)h0 + 1.0f); }
    if (n1 < N) { rs[n1] = ebase + excl + h0; dinv[n1] = rsqrtf((float)h1 + 1.0f); }

    hist[2 * t] = 0; hist[2 * t + 1] = 0;   // reuse as per-node cursors
    __syncthreads();

    for (int i = ebase + t; i < eend; i += 256) {
        int p = ebuf[i];
        int l = p & (BNODES - 1);
        int off = atomicAdd(&hist[l], 1);
        csr[ebase + rsl[l] + off] = ((unsigned)p) >> BSHIFT;
    }
}

// ================= layer 1 GEMM: hs1 (bf16 [N][64]) = (x @ W1) * dinv[row] =================
// 512 threads, 64 nodes/block. Register-tiled x via explicit float4 components (no address-taking!).

__launch_bounds__(512)
__global__ void k_gemm1(const float* __restrict__ x, const float* __restrict__ W1,
                        const float* __restrict__ dinv, uint2* __restrict__ hs1b, int N) {
    __shared__ float Ws[IN_DIM * HID];     // [k][f] 32 KB
    __shared__ float xs[64 * 132];         // 64 rows, pad 132
    const int t = threadIdx.x;
    const int base = blockIdx.x * 64;

    for (int i = t; i < IN_DIM * HID / 4; i += 512)
        ((float4*)Ws)[i] = ((const float4*)W1)[i];
    {
        const float4* s4 = (const float4*)(x + (size_t)base * IN_DIM);
        for (int i = t; i < 64 * IN_DIM / 4; i += 512) {
            int node = i >> 5;             // 32 float4 per row
            if (base + node < N) {
                float4 v = s4[i];
                *(float4*)&xs[node * 132 + (i & 31) * 4] = v;
            }
        }
    }
    __syncthreads();

    const int fq = t & 15;     // cols 4fq..4fq+3
    const int ng = t >> 4;     // 0..31 -> nodes 2ng, 2ng+1
    const float4* Wf4 = (const float4*)Ws;

    float4 a0 = {0,0,0,0}, a1 = {0,0,0,0};
    #pragma unroll
    for (int kb = 0; kb < IN_DIM; kb += 4) {
        float4 xv0 = *(const float4*)&xs[(2 * ng)     * 132 + kb];
        float4 xv1 = *(const float4*)&xs[(2 * ng + 1) * 132 + kb];
        float4 w;
        w = Wf4[(kb + 0) * 16 + fq];
        a0.x += xv0.x * w.x; a0.y += xv0.x * w.y; a0.z += xv0.x * w.z; a0.w += xv0.x * w.w;
        a1.x += xv1.x * w.x; a1.y += xv1.x * w.y; a1.z += xv1.x * w.z; a1.w += xv1.x * w.w;
        w = Wf4[(kb + 1) * 16 + fq];
        a0.x += xv0.y * w.x; a0.y += xv0.y * w.y; a0.z += xv0.y * w.z; a0.w += xv0.y * w.w;
        a1.x += xv1.y * w.x; a1.y += xv1.y * w.y; a1.z += xv1.y * w.z; a1.w += xv1.y * w.w;
        w = Wf4[(kb + 2) * 16 + fq];
        a0.x += xv0.z * w.x; a0.y += xv0.z * w.y; a0.z += xv0.z * w.z; a0.w += xv0.z * w.w;
        a1.x += xv1.z * w.x; a1.y += xv1.z * w.y; a1.z += xv1.z * w.z; a1.w += xv1.z * w.w;
        w = Wf4[(kb + 3) * 16 + fq];
        a0.x += xv0.w * w.x; a0.y += xv0.w * w.y; a0.z += xv0.w * w.z; a0.w += xv0.w * w.w;
        a1.x += xv1.w * w.x; a1.y += xv1.w * w.y; a1.z += xv1.w * w.z; a1.w += xv1.w * w.w;
    }
    int n0 = base + 2 * ng, n1 = n0 + 1;
    if (n0 < N) {
        float d0 = dinv[n0];
        hs1b[(size_t)n0 * 16 + fq] = make_uint2(bfp2(a0.x * d0, a0.y * d0), bfp2(a0.z * d0, a0.w * d0));
    }
    if (n1 < N) {
        float d1 = dinv[n1];
        hs1b[(size_t)n1 * 16 + fq] = make_uint2(bfp2(a1.x * d1, a1.y * d1), bfp2(a1.z * d1, a1.w * d1));
    }
}

// ================= CSR aggregation, layer 1: bf16 gather, fp32 accum, 4-deep MLP =================
// 8 lanes/node, each lane one uint4 (8 bf16 = 16B); row = 128B.

__launch_bounds__(256)
__global__ void k_agg1(const uint4* __restrict__ hs, const int* __restrict__ rs,
                       const int* __restrict__ csr, float* __restrict__ agg, int N) {
    int tid = blockIdx.x * 256 + threadIdx.x;
    int node = tid >> 3;
    if (node >= N) return;
    int lane = tid & 7;

    float fa[8] = {0,0,0,0,0,0,0,0};
    float fb[8] = {0,0,0,0,0,0,0,0};
    float fc[8] = {0,0,0,0,0,0,0,0};
    float fd[8] = {0,0,0,0,0,0,0,0};
    acc8(fa, hs[(size_t)node * 8 + lane]);   // self-loop
    int i = rs[node], end = rs[node + 1];
    for (; i + 4 <= end; i += 4) {
        int s0 = __builtin_nontemporal_load(csr + i);
        int s1 = __builtin_nontemporal_load(csr + i + 1);
        int s2 = __builtin_nontemporal_load(csr + i + 2);
        int s3 = __builtin_nontemporal_load(csr + i + 3);
        uint4 q0 = hs[(size_t)s0 * 8 + lane];
        uint4 q1 = hs[(size_t)s1 * 8 + lane];
        uint4 q2 = hs[(size_t)s2 * 8 + lane];
        uint4 q3 = hs[(size_t)s3 * 8 + lane];
        acc8(fa, q0); acc8(fb, q1); acc8(fc, q2); acc8(fd, q3);
    }
    if (i + 2 <= end) {
        int s0 = __builtin_nontemporal_load(csr + i);
        int s1 = __builtin_nontemporal_load(csr + i + 1);
        uint4 q0 = hs[(size_t)s0 * 8 + lane];
        uint4 q1 = hs[(size_t)s1 * 8 + lane];
        acc8(fa, q0); acc8(fb, q1);
        i += 2;
    }
    if (i < end) {
        int s0 = __builtin_nontemporal_load(csr + i);
        acc8(fa, hs[(size_t)s0 * 8 + lane]);
    }
    #pragma unroll
    for (int j = 0; j < 8; ++j) fa[j] += fb[j] + fc[j] + fd[j];
    float4* o = (float4*)(agg + (size_t)node * HID + lane * 8);
    o[0] = make_float4(fa[0], fa[1], fa[2], fa[3]);
    o[1] = make_float4(fa[4], fa[5], fa[6], fa[7]);
}

// ================= layer 2 GEMM: L1 = relu(dinv*agg1 + b1); hs2 (bf16 [N][32]) = (L1 @ W2) * dinv =================

__launch_bounds__(256)
__global__ void k_gemm2(const float* __restrict__ agg1, const float* __restrict__ W2,
                        const float* __restrict__ b1, const float* __restrict__ dinv,
                        uint2* __restrict__ hs2b) {
    __shared__ float Ws[HID * OUTD];
    __shared__ float L1s[32 * 68];
    const int t = threadIdx.x;
    const int base = blockIdx.x * 32;

    for (int i = t; i < HID * OUTD / 4; i += 256)
        ((float4*)Ws)[i] = ((const float4*)W2)[i];

    for (int e = t; e < 32 * HID; e += 256) {
        int n_l = e >> 6, k = e & 63;
        int gn = base + n_l;
        float v = dinv[gn] * agg1[(size_t)gn * HID + k] + b1[k];
        L1s[n_l * 68 + k] = fmaxf(v, 0.0f);
    }
    __syncthreads();

    const int fq = t & 7;
    const int nl = t >> 3;
    float4 a = {0,0,0,0};
    #pragma unroll 8
    for (int k = 0; k < HID; ++k) {
        float4 w = ((const float4*)Ws)[k * 8 + fq];
        float xv = L1s[nl * 68 + k];
        a.x += xv * w.x; a.y += xv * w.y; a.z += xv * w.z; a.w += xv * w.w;
    }
    int n = base + nl;
    float d = dinv[n];
    a.x *= d; a.y *= d; a.z *= d; a.w *= d;
    hs2b[(size_t)n * 8 + fq] = make_uint2(bfp2(a.x, a.y), bfp2(a.z, a.w));
}

// ================= CSR aggregation, layer 2 + fused epilogue: bf16 gather, 4-deep MLP =================
// 4 lanes/node, each lane one uint4 (8 bf16); row = 64B. out fp32 [N][32].

__launch_bounds__(256)
__global__ void k_agg2(const uint4* __restrict__ hs, const int* __restrict__ rs,
                       const int* __restrict__ csr, const float* __restrict__ dinv,
                       const float* __restrict__ b2, float* __restrict__ out, int N) {
    int tid = blockIdx.x * 256 + threadIdx.x;
    int node = tid >> 2;
    if (node >= N) return;
    int lane = tid & 3;

    float fa[8] = {0,0,0,0,0,0,0,0};
    float fb[8] = {0,0,0,0,0,0,0,0};
    float fc[8] = {0,0,0,0,0,0,0,0};
    float fd[8] = {0,0,0,0,0,0,0,0};
    acc8(fa, hs[(size_t)node * 4 + lane]);   // self-loop
    int i = rs[node], end = rs[node + 1];
    for (; i + 4 <= end; i += 4) {
        int s0 = __builtin_nontemporal_load(csr + i);
        int s1 = __builtin_nontemporal_load(csr + i + 1);
        int s2 = __builtin_nontemporal_load(csr + i + 2);
        int s3 = __builtin_nontemporal_load(csr + i + 3);
        uint4 q0 = hs[(size_t)s0 * 4 + lane];
        uint4 q1 = hs[(size_t)s1 * 4 + lane];
        uint4 q2 = hs[(size_t)s2 * 4 + lane];
        uint4 q3 = hs[(size_t)s3 * 4 + lane];
        acc8(fa, q0); acc8(fb, q1); acc8(fc, q2); acc8(fd, q3);
    }
    if (i + 2 <= end) {
        int s0 = __builtin_nontemporal_load(csr + i);
        int s1 = __builtin_nontemporal_load(csr + i + 1);
        uint4 q0 = hs[(size_t)s0 * 4 + lane];
        uint4 q1 = hs[(size_t)s1 * 4 + lane];
        acc8(fa, q0); acc8(fb, q1);
        i += 2;
    }
    if (i < end) {
        int s0 = __builtin_nontemporal_load(csr + i);
        acc8(fa, hs[(size_t)s0 * 4 + lane]);
    }
    float dn = dinv[node];
    const float4* bb4 = (const float4*)(b2 + lane * 8);
    float4 b0 = bb4[0], b1v = bb4[1];
    float4 o0, o1;
    o0.x = fmaxf((fa[0] + fb[0] + fc[0] + fd[0]) * dn + b0.x, 0.0f);
    o0.y = fmaxf((fa[1] + fb[1] + fc[1] + fd[1]) * dn + b0.y, 0.0f);
    o0.z = fmaxf((fa[2] + fb[2] + fc[2] + fd[2]) * dn + b0.z, 0.0f);
    o0.w = fmaxf((fa[3] + fb[3] + fc[3] + fd[3]) * dn + b0.w, 0.0f);
    o1.x = fmaxf((fa[4] + fb[4] + fc[4] + fd[4]) * dn + b1v.x, 0.0f);
    o1.y = fmaxf((fa[5] + fb[5] + fc[5] + fd[5]) * dn + b1v.y, 0.0f);
    o1.z = fmaxf((fa[6] + fb[6] + fc[6] + fd[6]) * dn + b1v.z, 0.0f);
    o1.w = fmaxf((fa[7] + fb[7] + fc[7] + fd[7]) * dn + b1v.w, 0.0f);
    float4* o = (float4*)(out + (size_t)node * OUTD + lane * 8);
    o[0] = o0;
    o[1] = o1;
}

// ================= launch =================

extern "C" void kernel_launch(void* const* d_in, const int* in_sizes, int n_in,
                              void* d_out, int out_size, void* d_ws, size_t ws_size,
                              hipStream_t stream) {
    const float* x  = (const float*)d_in[0];
    const int*   ei = (const int*)  d_in[1];
    const float* W1 = (const float*)d_in[2];
    const float* b1 = (const float*)d_in[3];
    const float* W2 = (const float*)d_in[4];
    const float* b2 = (const float*)d_in[5];

    const int N = in_sizes[0] / IN_DIM;   // 100000
    const int E = in_sizes[1] / 2;        // 1600000
    const int* srcI = ei;
    const int* dstI = ei + E;
    float* out = (float*)d_out;

    // workspace layout
    float* dinv         = (float*)d_ws;                       // 131072 slot
    int*   rs           = (int*)d_ws + 131072;                // N+1 (131072 slot)
    int*   bucketCnt    = rs + 131072;                        // 256
    int*   bucketBase   = bucketCnt + 256;                    // 256 (NB+1)
    int*   bucketCursor = bucketBase + 256;                   // 256
    int*   ebuf         = bucketCursor + 256;                 // E packed words
    int*   csr          = ebuf + E;                           // E
    uint2* hs1b         = (uint2*)(csr + E);                  // N*16 uint2 (bf16 [N][64]); reused as hs2b (N*8)
    float* agg1         = (float*)(hs1b + (size_t)N * 16);    // N*64 fp32

    hipMemsetAsync(bucketCnt, 0, NB * sizeof(int), stream);
    k_bcount  <<<256, 256, 0, stream>>>(dstI, bucketCnt, E);
    k_bscan   <<<1, 256, 0, stream>>>(bucketCnt, bucketBase, bucketCursor, rs, N, E);
    k_bscatter<<<(E + CHUNK - 1) / CHUNK, 256, 0, stream>>>(srcI, dstI, bucketCursor, ebuf, E);
    k_bfinal  <<<NB, 256, 0, stream>>>(ebuf, bucketBase, rs, dinv, csr, N);

    k_gemm1<<<(N + 63) / 64, 512, 0, stream>>>(x, W1, dinv, hs1b, N);
    k_agg1 <<<(N * 8 + 255) / 256, 256, 0, stream>>>((const uint4*)hs1b, rs, csr, agg1, N);
    k_gemm2<<<(N + 31) / 32, 256, 0, stream>>>(agg1, W2, b1, dinv, hs1b);   // hs1b reused as hs2b
    k_agg2 <<<(N * 4 + 255) / 256, 256, 0, stream>>>((const uint4*)hs1b, rs, csr, dinv, b2, out, N);
}

// Round 8
// 192.337 us; speedup vs baseline: 7.6329x; 7.6329x over previous
//
#include <hip/hip_runtime.h>

#define IN_DIM 128
#define HID    64
#define OUTD   32

#define BSHIFT 9
#define BNODES 512                 // 1 << BSHIFT
#define NB     196                 // ceil(100000 / 512)
#define CHUNK  4096                // edges per k_bscatter block

// ---- bf16 helpers (RNE pack, shift-unpack) ----

__device__ __forceinline__ unsigned bfp2(float x, float y) {
    unsigned a = __float_as_uint(x); a = a + 0x7FFF + ((a >> 16) & 1);
    unsigned b = __float_as_uint(y); b = b + 0x7FFF + ((b >> 16) & 1);
    return (a >> 16) | (b & 0xFFFF0000u);
}

__device__ __forceinline__ void acc8(float* f, uint4 q) {
    f[0] += __uint_as_float(q.x << 16); f[1] += __uint_as_float(q.x & 0xFFFF0000u);
    f[2] += __uint_as_float(q.y << 16); f[3] += __uint_as_float(q.y & 0xFFFF0000u);
    f[4] += __uint_as_float(q.z << 16); f[5] += __uint_as_float(q.z & 0xFFFF0000u);
    f[6] += __uint_as_float(q.w << 16); f[7] += __uint_as_float(q.w & 0xFFFF0000u);
}

#define FMA4(A, S, W) { A.x += (S)*(W).x; A.y += (S)*(W).y; A.z += (S)*(W).z; A.w += (S)*(W).w; }

// ================= Pass A: coarse bucket counts =================

__launch_bounds__(256)
__global__ void k_bcount(const int* __restrict__ dst, int* __restrict__ bucketCnt, int E) {
    __shared__ int h[NB];
    int t = threadIdx.x;
    for (int i = t; i < NB; i += 256) h[i] = 0;
    __syncthreads();
    int stride = gridDim.x * blockDim.x;
    for (int e = blockIdx.x * blockDim.x + t; e < E; e += stride)
        atomicAdd(&h[__builtin_nontemporal_load(dst + e) >> BSHIFT], 1);
    __syncthreads();
    for (int i = t; i < NB; i += 256)
        if (h[i]) atomicAdd(&bucketCnt[i], h[i]);
}

// ================= scan bucket counts -> bases & cursors =================

__global__ void k_bscan(const int* __restrict__ bucketCnt, int* __restrict__ bucketBase,
                        int* __restrict__ bucketCursor, int* __restrict__ rs, int N, int E) {
    __shared__ int sd[256];
    int t = threadIdx.x;
    int v = (t < NB) ? bucketCnt[t] : 0;
    sd[t] = v;
    __syncthreads();
    for (int off = 1; off < 256; off <<= 1) {
        int u = (t >= off) ? sd[t - off] : 0;
        __syncthreads();
        sd[t] += u;
        __syncthreads();
    }
    int excl = sd[t] - v;
    if (t < NB) { bucketBase[t] = excl; bucketCursor[t] = excl; }
    if (t == 0) { bucketBase[NB] = E; rs[N] = E; }
}

// ================= Pass B: scatter edges into buckets (packed src<<9 | dst_local) =================

__launch_bounds__(256)
__global__ void k_bscatter(const int* __restrict__ src, const int* __restrict__ dst,
                           int* __restrict__ bucketCursor, int* __restrict__ ebuf, int E) {
    __shared__ int h[NB];
    __shared__ int lbase[NB];
    __shared__ int lcur[NB];
    int t = threadIdx.x;
    int base = blockIdx.x * CHUNK;
    int end = min(base + CHUNK, E);
    for (int i = t; i < NB; i += 256) { h[i] = 0; lcur[i] = 0; }
    __syncthreads();
    for (int i = base + t; i < end; i += 256)
        atomicAdd(&h[dst[i] >> BSHIFT], 1);
    __syncthreads();
    for (int i = t; i < NB; i += 256)
        lbase[i] = h[i] ? atomicAdd(&bucketCursor[i], h[i]) : 0;
    __syncthreads();
    for (int i = base + t; i < end; i += 256) {
        int d = dst[i];
        int b = d >> BSHIFT;
        int off = atomicAdd(&lcur[b], 1);
        ebuf[lbase[b] + off] = (src[i] << BSHIFT) | (d & (BNODES - 1));
    }
}

// ================= Pass C: per-bucket fine CSR build + rs + dinv =================

__launch_bounds__(256)
__global__ void k_bfinal(const int* __restrict__ ebuf, const int* __restrict__ bucketBase,
                         int* __restrict__ rs, float* __restrict__ dinv,
                         int* __restrict__ csr, int N) {
    __shared__ int hist[BNODES];
    __shared__ int rsl[BNODES];
    __shared__ int ssum[256];
    int t = threadIdx.x;
    int b = blockIdx.x;
    int nodeBase = b << BSHIFT;
    int ebase = bucketBase[b], eend = bucketBase[b + 1];

    hist[t] = 0; hist[t + 256] = 0;
    __syncthreads();
    for (int i = ebase + t; i < eend; i += 256)
        atomicAdd(&hist[__builtin_nontemporal_load(ebuf + i) & (BNODES - 1)], 1);
    __syncthreads();

    int h0 = hist[2 * t], h1 = hist[2 * t + 1];
    ssum[t] = h0 + h1;
    __syncthreads();
    for (int off = 1; off < 256; off <<= 1) {
        int u = (t >= off) ? ssum[t - off] : 0;
        __syncthreads();
        ssum[t] += u;
        __syncthreads();
    }
    int excl = ssum[t] - h0 - h1;
    rsl[2 * t]     = excl;
    rsl[2 * t + 1] = excl + h0;

    int n0 = nodeBase + 2 * t, n1 = n0 + 1;
    if (n0 < N) { rs[n0] = ebase + excl;      dinv[n0] = rsqrtf((float)h0 + 1.0f); }
    if (n1 < N) { rs[n1] = ebase + excl + h0; dinv[n1] = rsqrtf((float)h1 + 1.0f); }

    hist[2 * t] = 0; hist[2 * t + 1] = 0;   // reuse as per-node cursors
    __syncthreads();

    for (int i = ebase + t; i < eend; i += 256) {
        int p = ebuf[i];
        int l = p & (BNODES - 1);
        int off = atomicAdd(&hist[l], 1);
        csr[ebase + rsl[l] + off] = ((unsigned)p) >> BSHIFT;
    }
}

// ================= layer 1 GEMM: hs1 (bf16 [N][64]) = (x @ W1) * dinv[row] =================
// 256 threads, 64 nodes/block, 4 rows x 4 cols per thread, unroll 2 to bound VGPR pressure.

__launch_bounds__(256)
__global__ void k_gemm1(const float* __restrict__ x, const float* __restrict__ W1,
                        const float* __restrict__ dinv, uint2* __restrict__ hs1b, int N) {
    __shared__ float Ws[IN_DIM * HID];     // [k][f] 32 KB
    __shared__ float xs[64 * 132];         // 64 rows, pad 132 (33.8 KB)
    const int t = threadIdx.x;
    const int base = blockIdx.x * 64;

    for (int i = t; i < IN_DIM * HID / 4; i += 256)
        ((float4*)Ws)[i] = ((const float4*)W1)[i];
    {
        const float4* s4 = (const float4*)(x + (size_t)base * IN_DIM);
        for (int i = t; i < 64 * IN_DIM / 4; i += 256) {
            int node = i >> 5;             // 32 float4 per row
            if (base + node < N)
                *(float4*)&xs[node * 132 + (i & 31) * 4] = s4[i];
        }
    }
    __syncthreads();

    const int fq = t & 15;     // col quad: cols 4fq..4fq+3
    const int ng = t >> 4;     // 0..15 -> rows 4ng..4ng+3
    const float4* Wf4 = (const float4*)Ws;
    const int r0 = 4 * ng, r1 = r0 + 1, r2 = r0 + 2, r3 = r0 + 3;

    float4 a0 = {0,0,0,0}, a1 = {0,0,0,0}, a2 = {0,0,0,0}, a3 = {0,0,0,0};
    #pragma unroll 2
    for (int kb = 0; kb < IN_DIM; kb += 4) {
        float4 x0 = *(const float4*)&xs[r0 * 132 + kb];
        float4 x1 = *(const float4*)&xs[r1 * 132 + kb];
        float4 x2 = *(const float4*)&xs[r2 * 132 + kb];
        float4 x3 = *(const float4*)&xs[r3 * 132 + kb];
        float4 w0 = Wf4[(kb + 0) * 16 + fq];
        float4 w1 = Wf4[(kb + 1) * 16 + fq];
        float4 w2 = Wf4[(kb + 2) * 16 + fq];
        float4 w3 = Wf4[(kb + 3) * 16 + fq];
        FMA4(a0, x0.x, w0); FMA4(a0, x0.y, w1); FMA4(a0, x0.z, w2); FMA4(a0, x0.w, w3);
        FMA4(a1, x1.x, w0); FMA4(a1, x1.y, w1); FMA4(a1, x1.z, w2); FMA4(a1, x1.w, w3);
        FMA4(a2, x2.x, w0); FMA4(a2, x2.y, w1); FMA4(a2, x2.z, w2); FMA4(a2, x2.w, w3);
        FMA4(a3, x3.x, w0); FMA4(a3, x3.y, w1); FMA4(a3, x3.z, w2); FMA4(a3, x3.w, w3);
    }
    int n0 = base + r0;
    if (n0 + 0 < N) { float d = dinv[n0 + 0]; hs1b[(size_t)(n0 + 0) * 16 + fq] = make_uint2(bfp2(a0.x * d, a0.y * d), bfp2(a0.z * d, a0.w * d)); }
    if (n0 + 1 < N) { float d = dinv[n0 + 1]; hs1b[(size_t)(n0 + 1) * 16 + fq] = make_uint2(bfp2(a1.x * d, a1.y * d), bfp2(a1.z * d, a1.w * d)); }
    if (n0 + 2 < N) { float d = dinv[n0 + 2]; hs1b[(size_t)(n0 + 2) * 16 + fq] = make_uint2(bfp2(a2.x * d, a2.y * d), bfp2(a2.z * d, a2.w * d)); }
    if (n0 + 3 < N) { float d = dinv[n0 + 3]; hs1b[(size_t)(n0 + 3) * 16 + fq] = make_uint2(bfp2(a3.x * d, a3.y * d), bfp2(a3.z * d, a3.w * d)); }
}

// ================= CSR aggregation, layer 1: bf16 gather, fp32 accum, 4-deep MLP =================
// 8 lanes/node, each lane one uint4 (8 bf16 = 16B); row = 128B.

__launch_bounds__(256)
__global__ void k_agg1(const uint4* __restrict__ hs, const int* __restrict__ rs,
                       const int* __restrict__ csr, float* __restrict__ agg, int N) {
    int tid = blockIdx.x * 256 + threadIdx.x;
    int node = tid >> 3;
    if (node >= N) return;
    int lane = tid & 7;

    float fa[8] = {0,0,0,0,0,0,0,0};
    float fb[8] = {0,0,0,0,0,0,0,0};
    float fc[8] = {0,0,0,0,0,0,0,0};
    float fd[8] = {0,0,0,0,0,0,0,0};
    acc8(fa, hs[(size_t)node * 8 + lane]);   // self-loop
    int i = rs[node], end = rs[node + 1];
    for (; i + 4 <= end; i += 4) {
        int s0 = __builtin_nontemporal_load(csr + i);
        int s1 = __builtin_nontemporal_load(csr + i + 1);
        int s2 = __builtin_nontemporal_load(csr + i + 2);
        int s3 = __builtin_nontemporal_load(csr + i + 3);
        uint4 q0 = hs[(size_t)s0 * 8 + lane];
        uint4 q1 = hs[(size_t)s1 * 8 + lane];
        uint4 q2 = hs[(size_t)s2 * 8 + lane];
        uint4 q3 = hs[(size_t)s3 * 8 + lane];
        acc8(fa, q0); acc8(fb, q1); acc8(fc, q2); acc8(fd, q3);
    }
    if (i + 2 <= end) {
        int s0 = __builtin_nontemporal_load(csr + i);
        int s1 = __builtin_nontemporal_load(csr + i + 1);
        uint4 q0 = hs[(size_t)s0 * 8 + lane];
        uint4 q1 = hs[(size_t)s1 * 8 + lane];
        acc8(fa, q0); acc8(fb, q1);
        i += 2;
    }
    if (i < end) {
        int s0 = __builtin_nontemporal_load(csr + i);
        acc8(fa, hs[(size_t)s0 * 8 + lane]);
    }
    #pragma unroll
    for (int j = 0; j < 8; ++j) fa[j] += fb[j] + fc[j] + fd[j];
    float4* o = (float4*)(agg + (size_t)node * HID + lane * 8);
    o[0] = make_float4(fa[0], fa[1], fa[2], fa[3]);
    o[1] = make_float4(fa[4], fa[5], fa[6], fa[7]);
}

// ================= layer 2 GEMM: L1 = relu(dinv*agg1 + b1); hs2 (bf16 [N][32]) = (L1 @ W2) * dinv =================

__launch_bounds__(256)
__global__ void k_gemm2(const float* __restrict__ agg1, const float* __restrict__ W2,
                        const float* __restrict__ b1, const float* __restrict__ dinv,
                        uint2* __restrict__ hs2b) {
    __shared__ float Ws[HID * OUTD];
    __shared__ float L1s[32 * 68];
    const int t = threadIdx.x;
    const int base = blockIdx.x * 32;

    for (int i = t; i < HID * OUTD / 4; i += 256)
        ((float4*)Ws)[i] = ((const float4*)W2)[i];

    for (int e = t; e < 32 * HID; e += 256) {
        int n_l = e >> 6, k = e & 63;
        int gn = base + n_l;
        float v = dinv[gn] * agg1[(size_t)gn * HID + k] + b1[k];
        L1s[n_l * 68 + k] = fmaxf(v, 0.0f);
    }
    __syncthreads();

    const int fq = t & 7;
    const int nl = t >> 3;
    float4 a = {0,0,0,0};
    #pragma unroll 8
    for (int k = 0; k < HID; ++k) {
        float4 w = ((const float4*)Ws)[k * 8 + fq];
        float xv = L1s[nl * 68 + k];
        a.x += xv * w.x; a.y += xv * w.y; a.z += xv * w.z; a.w += xv * w.w;
    }
    int n = base + nl;
    float d = dinv[n];
    a.x *= d; a.y *= d; a.z *= d; a.w *= d;
    hs2b[(size_t)n * 8 + fq] = make_uint2(bfp2(a.x, a.y), bfp2(a.z, a.w));
}

// ================= CSR aggregation, layer 2 + fused epilogue: bf16 gather, 4-deep MLP =================
// 4 lanes/node, each lane one uint4 (8 bf16); row = 64B. out fp32 [N][32].

__launch_bounds__(256)
__global__ void k_agg2(const uint4* __restrict__ hs, const int* __restrict__ rs,
                       const int* __restrict__ csr, const float* __restrict__ dinv,
                       const float* __restrict__ b2, float* __restrict__ out, int N) {
    int tid = blockIdx.x * 256 + threadIdx.x;
    int node = tid >> 2;
    if (node >= N) return;
    int lane = tid & 3;

    float fa[8] = {0,0,0,0,0,0,0,0};
    float fb[8] = {0,0,0,0,0,0,0,0};
    float fc[8] = {0,0,0,0,0,0,0,0};
    float fd[8] = {0,0,0,0,0,0,0,0};
    acc8(fa, hs[(size_t)node * 4 + lane]);   // self-loop
    int i = rs[node], end = rs[node + 1];
    for (; i + 4 <= end; i += 4) {
        int s0 = __builtin_nontemporal_load(csr + i);
        int s1 = __builtin_nontemporal_load(csr + i + 1);
        int s2 = __builtin_nontemporal_load(csr + i + 2);
        int s3 = __builtin_nontemporal_load(csr + i + 3);
        uint4 q0 = hs[(size_t)s0 * 4 + lane];
        uint4 q1 = hs[(size_t)s1 * 4 + lane];
        uint4 q2 = hs[(size_t)s2 * 4 + lane];
        uint4 q3 = hs[(size_t)s3 * 4 + lane];
        acc8(fa, q0); acc8(fb, q1); acc8(fc, q2); acc8(fd, q3);
    }
    if (i + 2 <= end) {
        int s0 = __builtin_nontemporal_load(csr + i);
        int s1 = __builtin_nontemporal_load(csr + i + 1);
        uint4 q0 = hs[(size_t)s0 * 4 + lane];
        uint4 q1 = hs[(size_t)s1 * 4 + lane];
        acc8(fa, q0); acc8(fb, q1);
        i += 2;
    }
    if (i < end) {
        int s0 = __builtin_nontemporal_load(csr + i);
        acc8(fa, hs[(size_t)s0 * 4 + lane]);
    }
    float dn = dinv[node];
    const float4* bb4 = (const float4*)(b2 + lane * 8);
    float4 b0 = bb4[0], b1v = bb4[1];
    float4 o0, o1;
    o0.x = fmaxf((fa[0] + fb[0] + fc[0] + fd[0]) * dn + b0.x, 0.0f);
    o0.y = fmaxf((fa[1] + fb[1] + fc[1] + fd[1]) * dn + b0.y, 0.0f);
    o0.z = fmaxf((fa[2] + fb[2] + fc[2] + fd[2]) * dn + b0.z, 0.0f);
    o0.w = fmaxf((fa[3] + fb[3] + fc[3] + fd[3]) * dn + b0.w, 0.0f);
    o1.x = fmaxf((fa[4] + fb[4] + fc[4] + fd[4]) * dn + b1v.x, 0.0f);
    o1.y = fmaxf((fa[5] + fb[5] + fc[5] + fd[5]) * dn + b1v.y, 0.0f);
    o1.z = fmaxf((fa[6] + fb[6] + fc[6] + fd[6]) * dn + b1v.z, 0.0f);
    o1.w = fmaxf((fa[7] + fb[7] + fc[7] + fd[7]) * dn + b1v.w, 0.0f);
    float4* o = (float4*)(out + (size_t)node * OUTD + lane * 8);
    o[0] = o0;
    o[1] = o1;
}

// ================= launch =================

extern "C" void kernel_launch(void* const* d_in, const int* in_sizes, int n_in,
                              void* d_out, int out_size, void* d_ws, size_t ws_size,
                              hipStream_t stream) {
    const float* x  = (const float*)d_in[0];
    const int*   ei = (const int*)  d_in[1];
    const float* W1 = (const float*)d_in[2];
    const float* b1 = (const float*)d_in[3];
    const float* W2 = (const float*)d_in[4];
    const float* b2 = (const float*)d_in[5];

    const int N = in_sizes[0] / IN_DIM;   // 100000
    const int E = in_sizes[1] / 2;        // 1600000
    const int* srcI = ei;
    const int* dstI = ei + E;
    float* out = (float*)d_out;

    // workspace layout
    float* dinv         = (float*)d_ws;                       // 131072 slot
    int*   rs           = (int*)d_ws + 131072;                // N+1 (131072 slot)
    int*   bucketCnt    = rs + 131072;                        // 256
    int*   bucketBase   = bucketCnt + 256;                    // 256 (NB+1)
    int*   bucketCursor = bucketBase + 256;                   // 256
    int*   ebuf         = bucketCursor + 256;                 // E packed words
    int*   csr          = ebuf + E;                           // E
    uint2* hs1b         = (uint2*)(csr + E);                  // N*16 uint2 (bf16 [N][64]); reused as hs2b (N*8)
    float* agg1         = (float*)(hs1b + (size_t)N * 16);    // N*64 fp32

    hipMemsetAsync(bucketCnt, 0, NB * sizeof(int), stream);
    k_bcount  <<<256, 256, 0, stream>>>(dstI, bucketCnt, E);
    k_bscan   <<<1, 256, 0, stream>>>(bucketCnt, bucketBase, bucketCursor, rs, N, E);
    k_bscatter<<<(E + CHUNK - 1) / CHUNK, 256, 0, stream>>>(srcI, dstI, bucketCursor, ebuf, E);
    k_bfinal  <<<NB, 256, 0, stream>>>(ebuf, bucketBase, rs, dinv, csr, N);

    k_gemm1<<<(N + 63) / 64, 256, 0, stream>>>(x, W1, dinv, hs1b, N);
    k_agg1 <<<(N * 8 + 255) / 256, 256, 0, stream>>>((const uint4*)hs1b, rs, csr, agg1, N);
    k_gemm2<<<(N + 31) / 32, 256, 0, stream>>>(agg1, W2, b1, dinv, hs1b);   // hs1b reused as hs2b
    k_agg2 <<<(N * 4 + 255) / 256, 256, 0, stream>>>((const uint4*)hs1b, rs, csr, dinv, b2, out, N);
}